// Round 2
// baseline (241.148 us; speedup 1.0000x reference)
//
#include <hip/hip_runtime.h>

// CIN cross-network, fused MFMA implementation (f16 inputs, fp32 accum).
// Round 2: 32x32x16 MFMA (2 batches packed along M), fused single prep
// kernel, explicit 2-stage pipeline, pk_mul broadcast, de-aliased LDS strides.
//
// y[b,n,d] = relu( sum_{m,h} x0[b,m,d] * xk[b,h,d] * W[m,h,n] )
// out[b, 64*l + n] = sum_d y  (per layer l)
//
// GEMM view per batch-pair: rows i=0..31 (i<16: batch p0 d=i; i>=16: p1,
// d=i-16), cols n=0..63 (2 tiles of 32), K = m*H + h.
// A[i][k] = x0[m,d_i]*xk[h,d_i] built on the fly from wave-private LDS;
// B = W repacked to per-lane fragment order (f16) in d_ws.
// No __syncthreads anywhere: all LDS regions are wave-private.

typedef _Float16 half8 __attribute__((ext_vector_type(8)));
typedef _Float16 half2v __attribute__((ext_vector_type(2)));
typedef float f32x16 __attribute__((ext_vector_type(16)));

#define OUT_STRIDE 192
#define X0B 648   // x0 batch stride (f16): 16B-multiple, +4-bank batch skew
#define X0R 40    // x0 row stride (d-major, 32 m + pad)
#define XKB 1160  // xk batch stride (f16): 16B-multiple, +4-bank batch skew
#define XKR 72    // xk row stride (d-major, 64 n + pad)

// ---------------------------------------------------------------------------
// Fused weight repack: fp32 W[m][h][n] -> f16 fragment order for 32x32x16.
// dst[layer_base + ((t*NKB + kb)*64 + lane)*8 + j] =
//     W[k -> (m,h)][n = t*32 + (lane&31)],  k = kb*16 + (lane>>5)*8 + j
__global__ void prep_w_all(const float* __restrict__ W0,
                           const float* __restrict__ W1,
                           const float* __restrict__ W2,
                           _Float16* __restrict__ dst) {
  int e = blockIdx.x * 256 + threadIdx.x;   // e < 327680
  const float* W;
  int logH, nkbLog, le;
  if (e < 65536)       { W = W0; logH = 5; nkbLog = 6; le = e; }
  else if (e < 196608) { W = W1; logH = 6; nkbLog = 7; le = e - 65536; }
  else                 { W = W2; logH = 6; nkbLog = 7; le = e - 196608; }
  int j    = le & 7;
  int lane = (le >> 3) & 63;
  int rest = le >> 9;
  int kb   = rest & ((1 << nkbLog) - 1);
  int t    = rest >> nkbLog;
  int k    = kb * 16 + ((lane >> 5) << 3) + j;
  int H    = 1 << logH;
  int m    = k >> logH, h = k & (H - 1);
  int n    = t * 32 + (lane & 31);
  dst[e] = (_Float16)W[(m * H + h) * 64 + n];
}

// ---------------------------------------------------------------------------
// One layer for one wave's 4 private batches (2 batch-pairs along M=32).
// LOGH: log2(H). VR/VB: f16 strides of the vector-source LDS region.
template<int LOGH, int VR, int VB, bool LAST>
__device__ __forceinline__ void run_layer(
    const _Float16* __restrict__ Wp, const _Float16* vsrc,
    const _Float16* x0s, _Float16* xkdst, float* __restrict__ out,
    long gb0, int loff, int lane)
{
  const int NIT = 1 << (LOGH + 1);        // K/16 = 2H
  const int HM  = (1 << (LOGH - 4)) - 1;  // kb->h0 block mask
  const int SH  = LOGH - 4;               // kb->m shift

  const int l31 = lane & 31;
  const int q2  = lane >> 5;
  const int r16 = lane & 15;
  const int b4  = (lane >> 4) & 1;

  // Per-batch-pair base pointers (lane-resolved).
  const _Float16* avb[2];
  const _Float16* xsb[2];
#pragma unroll
  for (int bp = 0; bp < 2; ++bp) {
    int bl = bp * 2 + b4;
    avb[bp] = vsrc + bl * VB + r16 * VR + q2 * 8;
    xsb[bp] = x0s + bl * X0B + r16 * X0R;
  }
  const _Float16* Wl = Wp + lane * 8;

  f32x16 acc[2][2];
#pragma unroll
  for (int bp = 0; bp < 2; ++bp)
#pragma unroll
    for (int t = 0; t < 2; ++t)
#pragma unroll
      for (int g = 0; g < 16; ++g) acc[bp][t][g] = 0.f;

  // Stage-0 prefetch.
  half8  Bc[2], avc[2];
  half2v xc[2];
#pragma unroll
  for (int t = 0; t < 2; ++t)
    Bc[t] = *(const half8*)(Wl + (size_t)(t * NIT) * 512);
#pragma unroll
  for (int bp = 0; bp < 2; ++bp) {
    avc[bp] = *(const half8*)(avb[bp]);
    _Float16 x = xsb[bp][0];
    xc[bp] = (half2v){x, x};
  }

#pragma unroll 4
  for (int kb = 0; kb < NIT; ++kb) {
    half8  Bn[2], avn[2];
    half2v xn[2];
    const bool more = (kb + 1) < NIT;
    if (more) {
      const int kn = kb + 1;
#pragma unroll
      for (int t = 0; t < 2; ++t)
        Bn[t] = *(const half8*)(Wl + (size_t)(t * NIT + kn) * 512);
      const int hb = (kn & HM) * 16;
      const int mn = kn >> SH;
#pragma unroll
      for (int bp = 0; bp < 2; ++bp) {
        avn[bp] = *(const half8*)(avb[bp] + hb);
        _Float16 x = xsb[bp][mn];
        xn[bp] = (half2v){x, x};
      }
    }
    // A-frag: af = av * broadcast(xs) via v_pk_mul_f16.
    half8 af[2];
#pragma unroll
    for (int bp = 0; bp < 2; ++bp) {
      half2v* ap = (half2v*)&af[bp];
      half2v* vp = (half2v*)&avc[bp];
#pragma unroll
      for (int j2 = 0; j2 < 4; ++j2) ap[j2] = vp[j2] * xc[bp];
    }
#pragma unroll
    for (int bp = 0; bp < 2; ++bp)
#pragma unroll
      for (int t = 0; t < 2; ++t)
        acc[bp][t] = __builtin_amdgcn_mfma_f32_32x32x16_f16(
            af[bp], Bc[t], acc[bp][t], 0, 0, 0);
    if (more) {
#pragma unroll
      for (int t = 0; t < 2; ++t) Bc[t] = Bn[t];
#pragma unroll
      for (int bp = 0; bp < 2; ++bp) { avc[bp] = avn[bp]; xc[bp] = xn[bp]; }
    }
  }

  // Epilogue. C/D layout: col(n) = lane&31, row = (g&3)+8*(g>>2)+4*q2.
  // g<8 -> row<16 -> batch half 0; g>=8 -> half 1. d = row&15.
#pragma unroll
  for (int bp = 0; bp < 2; ++bp) {
#pragma unroll
    for (int t = 0; t < 2; ++t) {
      float s[2] = {0.f, 0.f};
#pragma unroll
      for (int g = 0; g < 16; ++g) {
        float v = acc[bp][t][g];
        v = v > 0.f ? v : 0.f;
        const int half = g >> 3;
        const int g7 = g & 7;
        const int d = (g7 & 3) + 8 * (g7 >> 2) + 4 * q2;
        s[half] += v;
        if (!LAST)
          xkdst[(bp * 2 + half) * XKB + d * XKR + t * 32 + l31] = (_Float16)v;
      }
      s[0] += __shfl_xor(s[0], 32);
      s[1] += __shfl_xor(s[1], 32);
      const float sv = q2 ? s[1] : s[0];
      out[(gb0 + bp * 2 + q2) * OUT_STRIDE + loff + t * 32 + l31] = sv;
    }
  }
}

__global__ __launch_bounds__(256, 2) void cin_main(
    const float* __restrict__ emb, const _Float16* __restrict__ Wall,
    float* __restrict__ out)
{
  // x0: 16 batches * 648 f16 (16 d rows of stride 40)   = 20736 B
  // xk: 16 batches * 1160 f16 (16 d rows of stride 72)  = 37120 B
  __shared__ __align__(16) _Float16 lds[16 * X0B + 16 * XKB];
  const int lane = threadIdx.x & 63;
  const int wv = threadIdx.x >> 6;
  const long gb0 = (long)blockIdx.x * 16 + wv * 4;

  _Float16* x0w = &lds[wv * 4 * X0B];
  _Float16* xkw = &lds[16 * X0B + wv * 4 * XKB];

  // Stage this wave's 4 batches: read (m,d) fp32, write transposed (d,m) f16.
#pragma unroll
  for (int bb = 0; bb < 4; ++bb) {
    const float* src = emb + (gb0 + bb) * 512;
    _Float16* dstb = x0w + bb * X0B;
#pragma unroll
    for (int i = 0; i < 2; ++i) {
      int f = i * 256 + lane * 4;         // flat = m*16 + d, d aligned to 4
      float4 v = *(const float4*)(src + f);
      int m = f >> 4, d = f & 15;
      dstb[(d + 0) * X0R + m] = (_Float16)v.x;
      dstb[(d + 1) * X0R + m] = (_Float16)v.y;
      dstb[(d + 2) * X0R + m] = (_Float16)v.z;
      dstb[(d + 3) * X0R + m] = (_Float16)v.w;
    }
  }
  // All LDS regions are wave-private: program order + waitcnt suffice.

  run_layer<5, X0R, X0B, false>(Wall,          x0w, x0w, xkw, out, gb0, 0,   lane);
  run_layer<6, XKR, XKB, false>(Wall + 65536,  xkw, x0w, xkw, out, gb0, 64,  lane);
  run_layer<6, XKR, XKB, true >(Wall + 196608, xkw, x0w, xkw, out, gb0, 128, lane);
}

extern "C" void kernel_launch(void* const* d_in, const int* in_sizes, int n_in,
                              void* d_out, int out_size, void* d_ws, size_t ws_size,
                              hipStream_t stream) {
  const float* emb = (const float*)d_in[0];
  const float* W0  = (const float*)d_in[1];
  const float* W1  = (const float*)d_in[2];
  const float* W2  = (const float*)d_in[3];
  float* out = (float*)d_out;
  _Float16* ws = (_Float16*)d_ws;   // needs 327680 f16 = 640 KB

  // Single fused weight repack (327680 elements).
  prep_w_all<<<1280, 256, 0, stream>>>(W0, W1, W2, ws);

  // 16384 batches / 16 per block = 1024 blocks of 256 threads (4 waves x 4 b).
  cin_main<<<1024, 256, 0, stream>>>(emb, ws, out);
}

// Round 3
// 206.377 us; speedup vs baseline: 1.1685x; 1.1685x over previous
//
#include <hip/hip_runtime.h>

// CIN cross-network, fused MFMA implementation (f16 inputs, fp32 accum).
// Round 3: round-1 16x16x32 structure + A-vectors held in REGISTERS.
//
// Key identity: A[d][k] = x0[m(k),d] * xk[h(k),d] with h(k) = h0 + q*8 + j,
// h0 in {0,32}. Per lane only 2 distinct xk-vectors per batch per layer
// (1 in layer 1) -> load them once into VGPRs; the per-K variation is only
// the x0[m] scalar (pk_mul broadcast). This removes ~97% of the LDS A-read
// traffic that bounded rounds 1-2.
//
// Per-wave: 4 private batches; all LDS regions wave-private => NO barriers.

typedef _Float16 half8 __attribute__((ext_vector_type(8)));
typedef _Float16 half2v __attribute__((ext_vector_type(2)));
typedef float f32x4 __attribute__((ext_vector_type(4)));

#define OUT_STRIDE 192
#define X0R 32    // x0 row stride (f16): unpadded, 64B rows (16B-aligned)
#define X0B 512   // x0 batch stride
#define XKR 72    // xk row stride: 64 + 8 pad (16B-aligned)
#define XKB 1152  // xk batch stride

// ---------------------------------------------------------------------------
// Fused weight repack (round-1 verified 16x16 mapping, all 3 layers):
// dst[base + ((t*NKB + kb)*64 + lane)*8 + j] =
//     (f16) W[k -> (m,h)][n = t*16 + (lane&15)],  k = kb*32 + (lane>>4)*8 + j
__global__ void prep_w_all(const float* __restrict__ W0,
                           const float* __restrict__ W1,
                           const float* __restrict__ W2,
                           _Float16* __restrict__ dst) {
  int e = blockIdx.x * 256 + threadIdx.x;   // e < 327680
  const float* W;
  int logH, nkbLog, le;
  if (e < 65536)       { W = W0; logH = 5; nkbLog = 5; le = e; }
  else if (e < 196608) { W = W1; logH = 6; nkbLog = 6; le = e - 65536; }
  else                 { W = W2; logH = 6; nkbLog = 6; le = e - 196608; }
  int j    = le & 7;
  int lane = (le >> 3) & 63;
  int rr   = lane & 15, qq = lane >> 4;
  int rest = le >> 9;
  int kb   = rest & ((1 << nkbLog) - 1);
  int t    = rest >> nkbLog;
  int k    = kb * 32 + qq * 8 + j;
  int H    = 1 << logH;
  int m    = k >> logH, h = k & (H - 1);
  int n    = t * 16 + rr;
  dst[e] = (_Float16)W[(m * H + h) * 64 + n];
}

// ---------------------------------------------------------------------------
// One layer for one wave's 4 private batches.
// NHI: number of 32-wide h-blocks (1 for H=32, 2 for H=64). K-blocks: NKB=32*NHI.
// av[b][hi] = xk-vector (8 f16 at h = hi*32 + q*8 + j) held in registers.
template<int NHI, bool LAST>
__device__ __forceinline__ void run_layer(
    const _Float16* __restrict__ Wp, const half8 (&av)[4][NHI],
    const _Float16* x0s, _Float16* xkw, float* __restrict__ out,
    long gb0, int loff, int lane, int r, int q)
{
  const int NKB = 32 * NHI;
  f32x4 acc[4][4];
#pragma unroll
  for (int b = 0; b < 4; ++b)
#pragma unroll
    for (int t = 0; t < 4; ++t) acc[b][t] = (f32x4){0.f, 0.f, 0.f, 0.f};

  const _Float16* Wl = Wp + lane * 8;

#pragma unroll 2
  for (int m = 0; m < 32; ++m) {
    // x0 scalar per batch for this m (broadcast to half2 for v_pk_mul_f16).
    half2v xs2[4];
#pragma unroll
    for (int b = 0; b < 4; ++b) {
      _Float16 x = x0s[b * X0B + r * X0R + m];
      xs2[b] = (half2v){x, x};
    }
#pragma unroll
    for (int hi = 0; hi < NHI; ++hi) {
      const int kb = m * NHI + hi;
      half8 Bf[4];
#pragma unroll
      for (int t = 0; t < 4; ++t)
        Bf[t] = *(const half8*)(Wl + (size_t)(t * NKB + kb) * 512);
#pragma unroll
      for (int b = 0; b < 4; ++b) {
        half8 af;
        half2v* ap = (half2v*)&af;
        const half2v* vp = (const half2v*)&av[b][hi];
#pragma unroll
        for (int j2 = 0; j2 < 4; ++j2) ap[j2] = vp[j2] * xs2[b];
#pragma unroll
        for (int t = 0; t < 4; ++t)
          acc[b][t] = __builtin_amdgcn_mfma_f32_16x16x32_f16(
              af, Bf[t], acc[b][t], 0, 0, 0);
      }
    }
  }

  // Epilogue (round-1 verified). C/D layout: col n = r, row d = q*4 + reg.
#pragma unroll
  for (int b = 0; b < 4; ++b) {
#pragma unroll
    for (int t = 0; t < 4; ++t) {
      float s = 0.f;
#pragma unroll
      for (int rr = 0; rr < 4; ++rr) {
        float v = acc[b][t][rr];
        v = v > 0.f ? v : 0.f;
        s += v;
        if (!LAST)
          xkw[b * XKB + (q * 4 + rr) * XKR + t * 16 + r] = (_Float16)v;
      }
      s += __shfl_xor(s, 16);
      s += __shfl_xor(s, 32);
      if (q == 0)
        out[(gb0 + b) * OUT_STRIDE + loff + t * 16 + r] = s;
    }
  }
}

__global__ __launch_bounds__(256, 3) void cin_main(
    const float* __restrict__ emb, const _Float16* __restrict__ Wall,
    float* __restrict__ out)
{
  // x0: 16 batches * 512 f16 (16 d rows of stride 32) = 16384 B
  // xk: 16 batches * 1152 f16 (16 d rows of stride 72) = 36864 B
  // total 53248 B -> 3 blocks/CU.
  __shared__ __align__(16) _Float16 lds[16 * X0B + 16 * XKB];
  const int lane = threadIdx.x & 63;
  const int wv = threadIdx.x >> 6;
  const int r = lane & 15, q = lane >> 4;
  const long gb0 = (long)blockIdx.x * 16 + wv * 4;

  _Float16* x0w = &lds[wv * 4 * X0B];
  _Float16* xkw = &lds[16 * X0B + wv * 4 * XKB];

  // Stage this wave's 4 batches: read (m,d) fp32, write transposed (d,m) f16.
#pragma unroll
  for (int bb = 0; bb < 4; ++bb) {
    const float* src = emb + (gb0 + bb) * 512;
    _Float16* dstb = x0w + bb * X0B;
#pragma unroll
    for (int i = 0; i < 2; ++i) {
      int f = i * 256 + lane * 4;         // flat = m*16 + d, d aligned to 4
      float4 v = *(const float4*)(src + f);
      int m = f >> 4, d = f & 15;
      dstb[(d + 0) * X0R + m] = (_Float16)v.x;
      dstb[(d + 1) * X0R + m] = (_Float16)v.y;
      dstb[(d + 2) * X0R + m] = (_Float16)v.z;
      dstb[(d + 3) * X0R + m] = (_Float16)v.w;
    }
  }
  // All LDS regions are wave-private: program order + waitcnt suffice.

  // Layer 1: A-vectors from x0 (h = q*8+j, single h-block).
  half8 av1[4][1];
#pragma unroll
  for (int b = 0; b < 4; ++b)
    av1[b][0] = *(const half8*)(x0w + b * X0B + r * X0R + q * 8);
  run_layer<1, false>(Wall, av1, x0w, xkw, out, gb0, 0, lane, r, q);

  // Layer 2: A-vectors from xk (h = hi*32 + q*8 + j).
  half8 av2[4][2];
#pragma unroll
  for (int b = 0; b < 4; ++b)
#pragma unroll
    for (int hi = 0; hi < 2; ++hi)
      av2[b][hi] = *(const half8*)(xkw + b * XKB + r * XKR + hi * 32 + q * 8);
  run_layer<2, false>(Wall + 65536, av2, x0w, xkw, out, gb0, 64, lane, r, q);

  // Layer 3: reload A-vectors (layer 2 rewrote xk).
#pragma unroll
  for (int b = 0; b < 4; ++b)
#pragma unroll
    for (int hi = 0; hi < 2; ++hi)
      av2[b][hi] = *(const half8*)(xkw + b * XKB + r * XKR + hi * 32 + q * 8);
  run_layer<2, true>(Wall + 196608, av2, x0w, xkw, out, gb0, 128, lane, r, q);
}

extern "C" void kernel_launch(void* const* d_in, const int* in_sizes, int n_in,
                              void* d_out, int out_size, void* d_ws, size_t ws_size,
                              hipStream_t stream) {
  const float* emb = (const float*)d_in[0];
  const float* W0  = (const float*)d_in[1];
  const float* W1  = (const float*)d_in[2];
  const float* W2  = (const float*)d_in[3];
  float* out = (float*)d_out;
  _Float16* ws = (_Float16*)d_ws;   // needs 327680 f16 = 640 KB

  // Single fused weight repack (327680 elements).
  prep_w_all<<<1280, 256, 0, stream>>>(W0, W1, W2, ws);

  // 16384 batches / 16 per block = 1024 blocks of 256 threads (4 waves x 4 b).
  cin_main<<<1024, 256, 0, stream>>>(emb, ws, out);
}